// Round 9
// baseline (138.566 us; speedup 1.0000x reference)
//
#include <hip/hip_runtime.h>

#define POOLED 7
#define SCALE  0.25f
#define CCH    256
#define HH     128
#define WW     128
#define HW     (HH * WW)

#define NCH      16                    // channels per chunk
#define NCHUNK   2                     // chunks per block -> 32 channels/block
#define NBLK_PER_BOX (CCH / (NCH * NCHUNK))  // 8 blocks per box (MUST be 8: XCD affinity)
#define PATCH_H  15                    // row span <= 15
#define NV       5                     // float4 col-groups loaded per row (20 floats)
#define PIXROW   19                    // cols stored per row: rc 0..18 (max needed 17)
#define NPIX     (PATCH_H * PIXROW)    // 285 pixel slots
#define CHPAD    20                    // channel stride: 16 + 4 pad (16B-aligned reads)
#define ROWSTR   (PIXROW * CHPAD)      // 380 dwords per patch row

// ---------------------------------------------------------------------------
// Lessons enforced here (measured):
//  - blocks/box = 8 with slice = bx&7 <-> XCD 1:1. 4 blocks/box duplicated each
//    slice into two L2s: FETCH 31.9 -> 60.3 MB (round 7). Pairing boxes also
//    regressed (round 8: 44.7 -> 48.6 us, VALUBusy 42 -> 35%).
//  - plain __launch_bounds__(256): the (256,7) variant spilled prefetch regs
//    (WRITE_SIZE 49 -> 236 MB, 2.4x dur). Tripwire: main WRITE_SIZE ~= 49 MB.
//  - box sort cut FETCH 108 -> 31.9 MB (~compulsory).
// This round: hoist per-(box,pixel) bilinear weights/offsets into a precompute
// kernel (they were recomputed by 32 waves per box on the serial head of the
// hot kernel). ws-guarded; fallback = round-6 in-kernel path, bit-identical.
// ---------------------------------------------------------------------------
__global__ void box_sort_kernel(const float* __restrict__ boxes,
                                int* __restrict__ perm, int K)
{
    __shared__ int hist[16];
    __shared__ int base[16];
    int t = threadIdx.x;
    if (t < 16) hist[t] = 0;
    __syncthreads();
    for (int i = t; i < K; i += blockDim.x) {
        const float* bp = boxes + i * 5;
        int key = (((int)bp[0] & 3) << 2)
                | ((bp[2] >= 256.0f) ? 2 : 0)
                | ((bp[1] >= 256.0f) ? 1 : 0);
        atomicAdd(&hist[key], 1);
    }
    __syncthreads();
    if (t == 0) {
        int acc = 0;
        for (int j = 0; j < 16; ++j) { base[j] = acc; acc += hist[j]; }
    }
    __syncthreads();
    for (int i = t; i < K; i += blockDim.x) {
        const float* bp = boxes + i * 5;
        int key = (((int)bp[0] & 3) << 2)
                | ((bp[2] >= 256.0f) ? 2 : 0)
                | ((bp[1] >= 256.0f) ? 1 : 0);
        int pos = atomicAdd(&base[key], 1);
        perm[pos] = i;
    }
}

// ---- shared geometry (textually identical in both kernels -> bit-identical) ----
#define GEOM_BODY(BOXPTR)                                                     \
    float x1 = (BOXPTR)[1] * SCALE;                                           \
    float y1 = (BOXPTR)[2] * SCALE;                                           \
    float x2 = (BOXPTR)[3] * SCALE;                                           \
    float y2 = (BOXPTR)[4] * SCALE;                                           \
    float roi_w = fmaxf(x2 - x1, 1.0f);                                       \
    float roi_h = fmaxf(y2 - y1, 1.0f);                                       \
    float bin_w = roi_w * (1.0f / POOLED);                                    \
    float bin_h = roi_h * (1.0f / POOLED);                                    \
    int gw = (int)ceilf(roi_w * (1.0f / POOLED));                             \
    int gh = (int)ceilf(roi_h * (1.0f / POOLED));                             \
    float inv_gh = 1.0f / (float)gh;                                          \
    float inv_gw = 1.0f / (float)gw;                                          \
    float ymin = y1 + 0.5f * bin_h * inv_gh;                                  \
    float ymax = y1 + 6 * bin_h + ((gh - 1) + 0.5f) * bin_h * inv_gh;         \
    float xmin = x1 + 0.5f * bin_w * inv_gw;                                  \
    int ylo = min((int)fmaxf(ymin, 0.0f), HH - 1);                            \
    int xlo = min((int)fmaxf(xmin, 0.0f), WW - 1);                            \
    int xlo4 = xlo & ~3;                                                      \
    int ylmax = min((int)fmaxf(ymax, 0.0f), HH - 1);                          \
    int h_p = min(ylmax + 1, HH - 1) - ylo + 1;                               \
    if (h_p > PATCH_H) h_p = PATCH_H;

#define YSIDE_BODY(IYC, HY, LY, RT, RHT, YLO, HP) {                           \
        float y = yb + IYC * bin_h * inv_gh;                                  \
        bool vld = (y >= -1.0f) && (y <= (float)HH);                          \
        float yc = fmaxf(y, 0.0f);                                            \
        int yl = min((int)yc, HH - 1);                                        \
        int yh2 = min(yl + 1, HH - 1);                                        \
        float ly = (yl >= HH - 1) ? 0.0f : (yc - (float)yl);                  \
        HY = vld ? (1.0f - ly) : 0.0f;                                        \
        LY = vld ? ly : 0.0f;                                                 \
        int ry  = max(0, min(yl  - (YLO), (HP) - 1));                         \
        int ryh = max(0, min(yh2 - (YLO), (HP) - 1));                         \
        RT  = ry  * ROWSTR;                                                   \
        RHT = ryh * ROWSTR;                                                   \
    }
#define XSIDE_BODY(IXC, HX, LX, RT, RHT, X4) {                                \
        float x = xb + IXC * bin_w * inv_gw;                                  \
        bool vld = (x >= -1.0f) && (x <= (float)WW);                          \
        float xc = fmaxf(x, 0.0f);                                            \
        int xl = min((int)xc, WW - 1);                                        \
        int xh2 = min(xl + 1, WW - 1);                                        \
        float lx = (xl >= WW - 1) ? 0.0f : (xc - (float)xl);                  \
        HX = vld ? (1.0f - lx) : 0.0f;                                        \
        LX = vld ? lx : 0.0f;                                                 \
        int rxl = max(0, min(xl  - (X4), PIXROW - 1));                        \
        int rxh = max(0, min(xh2 - (X4), PIXROW - 1));                        \
        RT  = rxl * CHPAD;                                                    \
        RHT = rxh * CHPAD;                                                    \
    }

// combine 2 y-sides x 2 x-sides into 4 static sample slots (iy fastest)
#define COMBINE_BODY(GHM)                                                     \
    wa[0] = hy0*hx0; wb[0] = hy0*lx0; wc_[0] = ly0*hx0; wd[0] = ly0*lx0;      \
    oa[0] = ryT0+rxT0;  ob[0] = ryT0+rxhT0;                                   \
    oc[0] = ryhT0+rxT0; od[0] = ryhT0+rxhT0;                                  \
    {                                                                         \
        float hyS = (GHM) ? hy1 : hy0, lyS = (GHM) ? ly1 : ly0;               \
        int ryS = (GHM) ? ryT1 : ryT0, ryhS = (GHM) ? ryhT1 : ryhT0;          \
        float hxS = (GHM) ? hx0 : hx1, lxS = (GHM) ? lx0 : lx1;               \
        int rxS = (GHM) ? rxT0 : rxT1, rxhS = (GHM) ? rxhT0 : rxhT1;          \
        wa[1] = hyS*hxS; wb[1] = hyS*lxS; wc_[1] = lyS*hxS; wd[1] = lyS*lxS;  \
        oa[1] = ryS+rxS;  ob[1] = ryS+rxhS;                                   \
        oc[1] = ryhS+rxS; od[1] = ryhS+rxhS;                                  \
    }                                                                         \
    wa[2] = hy0*hx1; wb[2] = hy0*lx1; wc_[2] = ly0*hx1; wd[2] = ly0*lx1;      \
    oa[2] = ryT0+rxT1;  ob[2] = ryT0+rxhT1;                                   \
    oc[2] = ryhT0+rxT1; od[2] = ryhT0+rxhT1;                                  \
    wa[3] = hy1*hx1; wb[3] = hy1*lx1; wc_[3] = ly1*hx1; wd[3] = ly1*lx1;      \
    oa[3] = ryT1+rxT1;  ob[3] = ryT1+rxhT1;                                   \
    oc[3] = ryhT1+rxT1; od[3] = ryhT1+rxhT1;

// ---------------------------------------------------------------------------
// Per-(box, pixel) weight/offset table: [K][49][4] float4 + [K][49][4] int4.
// Was recomputed by 32 waves/box on the hot kernel's serial head.
// ---------------------------------------------------------------------------
__global__ __launch_bounds__(64) void wtab_kernel(
    const float* __restrict__ boxes,
    float4* __restrict__ wtab, int4* __restrict__ otab, int K)
{
    int k = blockIdx.x;
    int p = threadIdx.x;
    if (k >= K || p >= 49) return;
    const float* box = boxes + k * 5;
    GEOM_BODY(box)
    int ghm = gh - 1;
    int pw = p % POOLED;
    int ph = p / POOLED;
    float yb = y1 + ph * bin_h;
    float xb = x1 + pw * bin_w;

    float wa[4], wb[4], wc_[4], wd[4];
    int   oa[4], ob[4], oc[4], od[4];
    float hy0, ly0, hy1, ly1;
    int   ryT0, ryhT0, ryT1, ryhT1;
    float hx0, lx0, hx1, lx1;
    int   rxT0, rxhT0, rxT1, rxhT1;
    YSIDE_BODY(0.5f, hy0, ly0, ryT0, ryhT0, ylo, h_p)
    YSIDE_BODY(1.5f, hy1, ly1, ryT1, ryhT1, ylo, h_p)
    XSIDE_BODY(0.5f, hx0, lx0, rxT0, rxhT0, xlo4)
    XSIDE_BODY(1.5f, hx1, lx1, rxT1, rxhT1, xlo4)
    COMBINE_BODY(ghm)

    float4* wp = wtab + ((size_t)k * 49 + p) * 4;
    int4*   op = otab + ((size_t)k * 49 + p) * 4;
#pragma unroll
    for (int s = 0; s < 4; ++s) {
        wp[s] = make_float4(wa[s], wb[s], wc_[s], wd[s]);
        op[s] = make_int4(oa[s], ob[s], oc[s], od[s]);
    }
}

// Pixel-major LDS patch: patch[pix*CHPAD + ch], pix = ry*19 + rx (rx rel to
// 4-aligned xlo4). 22800 B -> 7 blocks/CU by LDS. Staging: one float4/lane,
// scatter 4 ds_write_b32; v=4 group stores only .x/.y/.z. Write banks <=3-way;
// reads ds_read_b128 at 80*pix + 16*cg bytes, 16B-aligned.
__global__ __launch_bounds__(256) void roi_align_kernel(
    const float* __restrict__ feat,   // [B, C, H, W]
    const float* __restrict__ boxes,  // [K, 5]
    float* __restrict__ out,          // [K, C, 7, 7]
    const int* __restrict__ perm,     // box processing order (or nullptr)
    const float4* __restrict__ wtab,  // per-(box,pixel) weights (or nullptr)
    const int4* __restrict__ otab,    // per-(box,pixel) LDS offsets (or nullptr)
    int K)
{
    __shared__ __align__(16) float patch[NPIX * CHPAD];   // 22800 B

    int bx = blockIdx.x;
    int kq = bx >> 3;
    int cb = (bx & 7) * (NCH * NCHUNK);     // channel base: slice = bx&7 <-> XCD
    if (kq >= K) return;
    int k = perm ? perm[kq] : kq;
    int t = threadIdx.x;

    const float* box = boxes + k * 5;
    int b = (int)box[0];
    GEOM_BODY(box)
    int mcr = min(WW - 1 - xlo4, (xlo - xlo4) + 14);
    float sc = inv_gh * inv_gw;

    // ---- block-uniform ints -> SGPRs ----
    int s_b   = __builtin_amdgcn_readfirstlane(b);
    int s_ylo = __builtin_amdgcn_readfirstlane(ylo);
    int s_x4  = __builtin_amdgcn_readfirstlane(xlo4);
    int s_hp  = __builtin_amdgcn_readfirstlane(h_p);
    int s_mcr = __builtin_amdgcn_readfirstlane(mcr);
    int s_ns  = __builtin_amdgcn_readfirstlane(gh * gw);
    int ghm   = __builtin_amdgcn_readfirstlane(gh - 1);

    int p  = t & 63;
    int pc = min(p, 48);
    int cg = t >> 6;                   // wave id = 4-channel group within chunk
    int lch = t >> 4;                  // 0..15 channel within chunk
    int sub = t & 15;

    // ---- staging mapping: one float4 per (lch, row, col-group) slot ----
    int lim = s_hp * NV;
    const float* gch0 = feat + (s_b * CCH + cb + lch) * HW;
    bool act[NV], actw[NV];
    int  goff[NV], la[NV];
#pragma unroll
    for (int i = 0; i < NV; ++i) {
        int idx = i * 16 + sub;        // 0..79, each (r,v) pair exactly once
        int r = idx / NV;
        int v = idx - r * NV;
        act[i]  = (idx < lim) && (4 * v <= s_mcr);
        actw[i] = act[i] && (v < 4);
        goff[i] = (s_ylo + r) * WW + min(s_x4 + 4 * v, WW - 4);
        la[i]   = (r * PIXROW + 4 * v) * CHPAD + lch;
    }

    // ---- issue chunk-0 staging loads ASAP ----
    float4 u0[NV];
#pragma unroll
    for (int i = 0; i < NV; ++i)
        if (act[i]) u0[i] = *(const float4*)(gch0 + goff[i]);

    // ---- weights/offsets: table load (overlaps u0 latency) or compute ----
    float wa[4], wb[4], wc_[4], wd[4];
    int   oa[4], ob[4], oc[4], od[4];
    if (otab) {
        const float4* wp = wtab + ((size_t)k * 49 + pc) * 4;
        const int4*   op = otab + ((size_t)k * 49 + pc) * 4;
#pragma unroll
        for (int s = 0; s < 4; ++s) {
            if (s >= s_ns) break;      // uniform trip count
            float4 w = wp[s]; int4 o = op[s];
            wa[s] = w.x; wb[s] = w.y; wc_[s] = w.z; wd[s] = w.w;
            oa[s] = o.x; ob[s] = o.y; oc[s] = o.z; od[s] = o.w;
        }
    } else {
        int pw = pc % POOLED;
        int ph = pc / POOLED;
        float yb = y1 + ph * bin_h;
        float xb = x1 + pw * bin_w;
        float hy0, ly0, hy1, ly1;
        int   ryT0, ryhT0, ryT1, ryhT1;
        float hx0, lx0, hx1, lx1;
        int   rxT0, rxhT0, rxT1, rxhT1;
        YSIDE_BODY(0.5f, hy0, ly0, ryT0, ryhT0, s_ylo, s_hp)
        YSIDE_BODY(1.5f, hy1, ly1, ryT1, ryhT1, s_ylo, s_hp)
        XSIDE_BODY(0.5f, hx0, lx0, rxT0, rxhT0, s_x4)
        XSIDE_BODY(1.5f, hx1, lx1, rxT1, rxhT1, s_x4)
        COMBINE_BODY(ghm)
    }

    // ---- chunk 0: write to LDS (waits u0) ----
#pragma unroll
    for (int i = 0; i < NV; ++i)
        if (act[i]) {
            float* lp = patch + la[i];
            lp[0]         = u0[i].x;
            lp[CHPAD]     = u0[i].y;
            lp[2 * CHPAD] = u0[i].z;
            if (actw[i]) lp[3 * CHPAD] = u0[i].w;
        }

    // ---- issue chunk-1 loads; latency hides under compute 0 ----
    const float* gch1 = gch0 + NCH * HW;
    float4 u1[NV];
#pragma unroll
    for (int i = 0; i < NV; ++i)
        if (act[i]) u1[i] = *(const float4*)(gch1 + goff[i]);

    __syncthreads();

#define BILIN(S) {                                                      \
        float4 va = *(const float4*)(cp + oa[S]);                       \
        float4 vb = *(const float4*)(cp + ob[S]);                       \
        float4 vc = *(const float4*)(cp + oc[S]);                       \
        float4 vd = *(const float4*)(cp + od[S]);                       \
        float w1 = wa[S], w2 = wb[S], w3 = wc_[S], w4 = wd[S];          \
        acc.x += w1 * va.x + w2 * vb.x + w3 * vc.x + w4 * vd.x;         \
        acc.y += w1 * va.y + w2 * vb.y + w3 * vc.y + w4 * vd.y;         \
        acc.z += w1 * va.z + w2 * vb.z + w3 * vc.z + w4 * vd.z;         \
        acc.w += w1 * va.w + w2 * vb.w + w3 * vc.w + w4 * vd.w;         \
    }
#define COMPUTE(CHB) {                                                  \
        float4 acc = {0.0f, 0.0f, 0.0f, 0.0f};                          \
        const float* cp = patch + cg * 4;                               \
        BILIN(0)                                                        \
        if (s_ns > 1) BILIN(1)                                          \
        if (s_ns > 2) { BILIN(2) BILIN(3) }                             \
        int ob_ = (k * CCH + cb + (CHB) + cg * 4) * 49 + p;             \
        out[ob_]          = acc.x * sc;                                 \
        out[ob_ + 49]     = acc.y * sc;                                 \
        out[ob_ + 2 * 49] = acc.z * sc;                                 \
        out[ob_ + 3 * 49] = acc.w * sc;                                 \
    }

    // ---- compute chunk 0 ----
    if (p < 49) COMPUTE(0)

    __syncthreads();                   // WAR: compute 0 done before overwrite

    // ---- chunk 1: write (loads already in flight) ----
#pragma unroll
    for (int i = 0; i < NV; ++i)
        if (act[i]) {
            float* lp = patch + la[i];
            lp[0]         = u1[i].x;
            lp[CHPAD]     = u1[i].y;
            lp[2 * CHPAD] = u1[i].z;
            if (actw[i]) lp[3 * CHPAD] = u1[i].w;
        }
    __syncthreads();

    // ---- compute chunk 1 ----
    if (p < 49) COMPUTE(NCH)
}

extern "C" void kernel_launch(void* const* d_in, const int* in_sizes, int n_in,
                              void* d_out, int out_size, void* d_ws, size_t ws_size,
                              hipStream_t stream) {
    const float* feat  = (const float*)d_in[0];
    const float* boxes = (const float*)d_in[1];
    float* out = (float*)d_out;

    int K = in_sizes[1] / 5;
    int* perm = nullptr;
    float4* wtab = nullptr;
    int4*   otab = nullptr;

    size_t permB = ((size_t)K * sizeof(int) + 511) & ~(size_t)511;
    size_t tabB  = (size_t)K * 49 * 4 * 16;   // each table: K*49*4 vec4

    if (d_ws && ws_size >= permB) {
        perm = (int*)d_ws;
        box_sort_kernel<<<1, 1024, 0, stream>>>(boxes, perm, K);
    }
    if (d_ws && ws_size >= permB + 2 * tabB) {
        wtab = (float4*)((char*)d_ws + permB);
        otab = (int4*)((char*)d_ws + permB + tabB);
        wtab_kernel<<<K, 64, 0, stream>>>(boxes, wtab, otab, K);
    }

    int blocks = K * NBLK_PER_BOX;     // (box, 32-channel slice)
    roi_align_kernel<<<blocks, 256, 0, stream>>>(feat, boxes, out, perm,
                                                 wtab, otab, K);
}